// Round 9
// baseline (132.953 us; speedup 1.0000x reference)
//
#include <hip/hip_runtime.h>

// Involution2d: B=8, C=256, G=4 (Cpg=64), H=W=Ho=Wo=64, K=7, PAD=3, STRIDE=1.
// out[b, g*64+c, y, x] = sum_{kh,kw} in[b, g*64+c, y+kh-3, x+kw-3] * w[b,g,kh,kw,y,x] + bias[g*64+c]
//
// Round-9. Allocator law (final form, r0-r8): whenever register demand CAN be
// squeezed to 64, this toolchain grants exactly 64 — regardless of block
// size, launch_bounds, waves_per_eu, or asm pins (r7 spilled rather than
// grant more). So: design FOR 64 regs and hide the just-in-time weight-load
// latency with TLP instead of per-wave pipelining.
//  - LDS stride 24 -> 18 float4 (zero waste). Reads stay conflict-free:
//    phase = (18*row + tx+m) % 8 = (2*(ty+kh) + tx+m) % 8; over a wave
//    (ty 0..3, tx 0..15) each of 8 phases gets exactly 8 lanes. Staging
//    writes become LINEAR (lds4[ch*396+e], phase = e%8, uniform). No swizzle.
//  - LDS 33.8KB -> 25.3KB: 6 blocks/CU x 4 waves = 24-wave cap (75%) vs
//    r6's 16-wave cap (realized 33%). 1.5x TLP at identical per-thread work.
//  - Register demand ~60 fits the granted 64 with no spill: jit weights 28
//    + acc 16 + vals 12 + addr. Bias folded into acc init (no epilogue adds).
//  - ROWS=16 kept (r8 proved ROWS=8's halo/prologue costs ~27%).
// Decisive readouts: OccupancyPercent 55-75, WRITE_SIZE == 33.5MB (no spill).

#define BLK_X 16
#define BLK_Y 16
#define NTHR  256
#define NC    4
#define ROWS  16                  // output rows per block (= BLK_Y)
#define S_ROWS 22                 // ROWS + 6 halo
#define ST_F4 18                  // float4 per staged row, ZERO waste
#define S_CH_F4 (S_ROWS * ST_F4)  // 396 float4 per channel
#define SEGS S_CH_F4              // staging is exactly linear

__global__ __launch_bounds__(NTHR, 4)
void involution_kernel(const float* __restrict__ in,
                       const float* __restrict__ w,
                       const float* __restrict__ bias,
                       float* __restrict__ out) {
    __shared__ float4 lds4[NC * S_CH_F4];   // 25,344 B -> 6 blocks/CU

    const int tx  = threadIdx.x;            // 0..15 (x-quad)
    const int ty  = threadIdx.y;            // 0..15 (row)
    const int tid = ty * BLK_X + tx;        // 0..255
    const int x0  = tx * 4;
    const int Y0  = blockIdx.x * ROWS;
    const int y   = Y0 + ty;
    const int c0  = blockIdx.y * NC;
    const int bz  = blockIdx.z;             // b*4 + g
    const int g   = bz & 3;

    const float* inb  = in  + (size_t)bz * 64 * 4096;
    float*       outb = out + (size_t)bz * 64 * 4096;
    const float* wb   = w   + (size_t)bz * 49 * 4096 + y * 64 + x0;

    // ---- stage NC channels once; LINEAR layout, single barrier ----
    // e = row*18 + t; t=0/17 are zero halo cols; t=1..16 -> gx = 4(t-1)+i;
    // row -> gy = Y0 + row - 3 (zero outside image).
    #pragma unroll
    for (int ch = 0; ch < NC; ++ch) {
        const float* p = inb + (size_t)(c0 + ch) * 4096;
        #pragma unroll
        for (int j = 0; j < 2; ++j) {
            int e = tid + j * NTHR;          // 0..511, guard < 396
            if (e < SEGS) {
                int row = e / 18;
                int t   = e - row * 18;
                int gy  = Y0 + row - 3;
                float4 v = make_float4(0.f, 0.f, 0.f, 0.f);
                if (t >= 1 && t <= 16 && gy >= 0 && gy < 64)
                    v = *(const float4*)(p + gy * 64 + (t - 1) * 4);
                lds4[ch * S_CH_F4 + e] = v;
            }
        }
    }

    // bias folded into accumulator init (no epilogue adds, no bvs array)
    float acc[NC][4];
    #pragma unroll
    for (int c = 0; c < NC; ++c) {
        const float bv = bias[g * 64 + c0 + c];
        acc[c][0] = bv; acc[c][1] = bv; acc[c][2] = bv; acc[c][3] = bv;
    }

    __syncthreads();

    // ---- main loop: jit weight stream (7 float4 live), TLP hides latency --
    #pragma unroll
    for (int kh = 0; kh < 7; ++kh) {
        float4 wv[7];
        #pragma unroll
        for (int kw = 0; kw < 7; ++kw)
            wv[kw] = *(const float4*)(wb + (size_t)(kh * 7 + kw) * 4096);

        const int row = ty + kh;             // staged row 0..21
        #pragma unroll
        for (int ch = 0; ch < NC; ++ch) {
            const float4* lp = lds4 + ch * S_CH_F4 + row * ST_F4 + tx;
            float4 v0 = lp[0];
            float4 v1 = lp[1];
            float4 v2 = lp[2];
            float vals[12] = {v0.x, v0.y, v0.z, v0.w,
                              v1.x, v1.y, v1.z, v1.w,
                              v2.x, v2.y, v2.z, v2.w};
            #pragma unroll
            for (int kw = 0; kw < 7; ++kw) {
                acc[ch][0] += vals[kw + 1] * wv[kw].x;
                acc[ch][1] += vals[kw + 2] * wv[kw].y;
                acc[ch][2] += vals[kw + 3] * wv[kw].z;
                acc[ch][3] += vals[kw + 4] * wv[kw].w;
            }
        }
    }

    // ---- epilogue (bias already accumulated) ----
    #pragma unroll
    for (int c = 0; c < NC; ++c) {
        float4 o;
        o.x = acc[c][0]; o.y = acc[c][1]; o.z = acc[c][2]; o.w = acc[c][3];
        *(float4*)(outb + (size_t)(c0 + c) * 4096 + y * 64 + x0) = o;
    }
}

extern "C" void kernel_launch(void* const* d_in, const int* in_sizes, int n_in,
                              void* d_out, int out_size, void* d_ws, size_t ws_size,
                              hipStream_t stream) {
    const float* in   = (const float*)d_in[0];  // (8,256,64,64)
    const float* wgt  = (const float*)d_in[1];  // (8,4,7,7,64,64)
    const float* bias = (const float*)d_in[2];  // (256,)
    float* out = (float*)d_out;                 // (8,256,64,64)

    dim3 block(BLK_X, BLK_Y, 1);                 // 256 threads = 4 waves
    dim3 grid(64 / ROWS, 64 / NC, 32);           // (4, 16, 32) = 2048 blocks
    involution_kernel<<<grid, block, 0, stream>>>(in, wgt, bias, out);
}